// Round 13
// baseline (174.752 us; speedup 1.0000x reference)
//
#include <hip/hip_runtime.h>
#include <math.h>

#define T_DIM 4096
#define B_DIM 16
#define P_DIM 512
#define H_DIM 512
#define M_DIM (T_DIM * B_DIM)   // 65536
#define BP (B_DIM * P_DIM)      // 8192
#define BP4 (BP / 4)            // 2048
#define P4 (P_DIM / 4)          // 128

#define KBYTES (H_DIM * 2)      // f16 row bytes = 1024
#define BK 64
#define NKT (H_DIM / BK)        // 8 k-tiles

// fused path: chunk = 8 timesteps (one 128-row GEMM tile)
#define CLEN_F 8
#define CHUNKS_F (T_DIM / CLEN_F)   // 512
#define GROUP 16                    // chunks per group in carry hierarchy
#define NGROUPS (CHUNKS_F / GROUP)  // 32
// fallback (fp32) path: chunk = 64 timesteps
#define CLEN_S 64
#define CHUNKS_S (T_DIM / CLEN_S)   // 64

#define SCALE_B 1048576.0f          // 2^20: lifts b_bar out of f16 subnormal range
#define INV_SCALE_B (1.0f / 1048576.0f)

typedef _Float16 f16x8 __attribute__((ext_vector_type(8)));
typedef float f32x4 __attribute__((ext_vector_type(4)));

__device__ __forceinline__ void gload16(const void* g, void* l) {
    __builtin_amdgcn_global_load_lds(
        (const __attribute__((address_space(1))) void*)(uintptr_t)g,
        (__attribute__((address_space(3))) void*)(uint32_t)(uintptr_t)l,
        16, 0, 0);
}

// ---------------------------------------------------------------------------
// Kernel A: discretization + per-p scan coefficients.
// ---------------------------------------------------------------------------
__global__ __launch_bounds__(256) void precompute_kernel(
    const float* __restrict__ log_neg_a,
    const float* __restrict__ b,
    const float* __restrict__ log_dt,
    float* __restrict__ b_bar,
    _Float16* __restrict__ b_bar16,
    float* __restrict__ a_bar,
    float* __restrict__ aL8,
    float* __restrict__ aL128,
    float* __restrict__ aL64,
    float* __restrict__ aL8pow,
    int write16) {
    int idx = blockIdx.x * blockDim.x + threadIdx.x;
    if (idx >= P_DIM * H_DIM) return;
    int p = idx >> 9;
    float dt = expf(log_dt[p]);
    float a  = -expf(log_neg_a[p]);
    float x  = dt * a;
    float scale = (expm1f(x) / a) * dt;
    float bb = scale * b[idx];
    b_bar[idx] = bb;
    if (write16) b_bar16[idx] = (_Float16)(bb * SCALE_B);
    if ((idx & (H_DIM - 1)) == 0) {
        a_bar[p] = expf(x);
        float l8 = expf(x * 8.0f);
        aL8[p]   = l8;
        aL128[p] = expf(x * 128.0f);
        aL64[p]  = expf(x * 64.0f);
        float pw = 1.0f;
        for (int j = 0; j < GROUP; ++j) {
            aL8pow[j * P_DIM + p] = pw;
            pw *= l8;
        }
    }
}

// ---------------------------------------------------------------------------
// Kernel B (fast): f16 MFMA NT GEMM, 128x64 tile, A reg-staged f32->f16
// (convert pass eliminated), B16 via global_load_lds, XCD swizzle,
// fused 8-step chunk-local time scan. Carry == last-timestep output row
// (not stored separately).
// A staging (R6-proven pair): writer puts global k-chunk slot8 of row r at
// LDS slot slot8^(r&7); reader reads slot g^(row&7) for logical chunk g.
// ---------------------------------------------------------------------------
__global__ __launch_bounds__(256, 6) void gemm_regA_scan_kernel(
    const float* __restrict__ A,
    const char* __restrict__ B16,
    const float* __restrict__ a_bar,
    float* __restrict__ Cout) {
    __shared__ char As[128 * BK * 2];   // 16 KB (f16 tile)
    __shared__ char Bs[64 * BK * 2];    // 8 KB

    const int tid  = threadIdx.x;
    const int lane = tid & 63;
    const int wid  = tid >> 6;

    // T1 swizzle: 4096 blocks, l%8 -> XCD; 8 col-blocks of a row-panel
    // run consecutively on one XCD.
    const int l   = blockIdx.x;           // 0..4095
    const int k8  = l & 7;
    const int j   = l >> 3;               // 0..511
    const int by  = k8 * 64 + (j >> 3);   // row-block (= chunk id), 0..511
    const int bx  = j & 7;                // col-block, 0..7
    const int rowBase = by * 128;
    const int colBase = bx * 64;

    // A staging addresses (f32 source, f16 swizzled LDS dest)
    const int arow  = tid >> 3;           // 0..31
    const int slot8 = tid & 7;            // 8-float unit in the 64-float slab
    const float* gA = A + (size_t)(rowBase + arow) * H_DIM + slot8 * 8;
    const int adst  = arow * 128 + ((slot8 ^ (arow & 7)) << 4);

    // B staging via global_load_lds (R12-proven)
    const int srow  = tid >> 3;           // 0..31
    const int scolb = ((tid & 7) << 4) ^ ((srow & 7) << 4);
    const char* gB  = B16 + (size_t)(colBase + srow) * KBYTES + scolb;

    f32x4 acc[4][2];
#pragma unroll
    for (int m2 = 0; m2 < 4; ++m2)
#pragma unroll
        for (int n2 = 0; n2 < 2; ++n2)
            acc[m2][n2] = (f32x4){0.f, 0.f, 0.f, 0.f};

    const int wr = wid >> 1;   // row half (64 rows = 4 timesteps)
    const int wc = wid & 1;    // col half (32 cols)

    for (int kt = 0; kt < NKT; ++kt) {
        // B: async direct-to-LDS (2 issues x 256 chunks)
#pragma unroll
        for (int i = 0; i < 2; ++i)
            gload16(gB + (size_t)i * 32 * KBYTES, Bs + (i * 256 + tid) * 16);
        // A: reg-staged f32 loads (issue all 8 float4 loads first)
        float4 a0[4], a1[4];
#pragma unroll
        for (int i = 0; i < 4; ++i) {
            const float* src = gA + (size_t)i * 32 * H_DIM;
            a0[i] = *(const float4*)(src);
            a1[i] = *(const float4*)(src + 4);
        }
        // convert + swizzled ds_write
#pragma unroll
        for (int i = 0; i < 4; ++i) {
            f16x8 v;
            v[0] = (_Float16)a0[i].x; v[1] = (_Float16)a0[i].y;
            v[2] = (_Float16)a0[i].z; v[3] = (_Float16)a0[i].w;
            v[4] = (_Float16)a1[i].x; v[5] = (_Float16)a1[i].y;
            v[6] = (_Float16)a1[i].z; v[7] = (_Float16)a1[i].w;
            *(f16x8*)(As + i * 32 * 128 + adst) = v;
        }
        gA += BK;       // next 64-float k-slab
        gB += BK * 2;
        __syncthreads();

#pragma unroll
        for (int kk = 0; kk < 2; ++kk) {
            const int kbyte = kk * 64 + ((lane >> 4) << 4);
            f16x8 af[4], bf[2];
#pragma unroll
            for (int m2 = 0; m2 < 4; ++m2) {
                int row = wr * 64 + m2 * 16 + (lane & 15);
                af[m2] = *(const f16x8*)(As + row * 128 + (kbyte ^ ((row & 7) << 4)));
            }
#pragma unroll
            for (int n2 = 0; n2 < 2; ++n2) {
                int col = wc * 32 + n2 * 16 + (lane & 15);
                bf[n2] = *(const f16x8*)(Bs + col * 128 + (kbyte ^ ((col & 7) << 4)));
            }
#pragma unroll
            for (int m2 = 0; m2 < 4; ++m2)
#pragma unroll
                for (int n2 = 0; n2 < 2; ++n2)
                    acc[m2][n2] = __builtin_amdgcn_mfma_f32_16x16x32_f16(
                        af[m2], bf[n2], acc[m2][n2], 0, 0, 0);
        }
        __syncthreads();
    }

    // ---- fused chunk-local scan over the block's 8 timesteps ----
    float* lds_z = (float*)As;               // [16 b][64 p_local]
    const int pl = wc * 32 + (lane & 15);

    float ab[2];
#pragma unroll
    for (int n2 = 0; n2 < 2; ++n2) ab[n2] = a_bar[colBase + pl + n2 * 16];

    if (wr == 0) {
#pragma unroll
        for (int n2 = 0; n2 < 2; ++n2)
#pragma unroll
            for (int r = 0; r < 4; ++r) {
                float z = 0.f;
#pragma unroll
                for (int m2 = 0; m2 < 4; ++m2) {
                    z = fmaf(ab[n2], z, acc[m2][n2][r]);
                    acc[m2][n2][r] = z;
                }
                lds_z[((lane >> 4) * 4 + r) * 64 + pl + n2 * 16] = z;
            }
    }
    __syncthreads();
    if (wr == 1) {
#pragma unroll
        for (int n2 = 0; n2 < 2; ++n2)
#pragma unroll
            for (int r = 0; r < 4; ++r) {
                float z = lds_z[((lane >> 4) * 4 + r) * 64 + pl + n2 * 16];
#pragma unroll
                for (int m2 = 0; m2 < 4; ++m2) {
                    z = fmaf(ab[n2], z, acc[m2][n2][r]);
                    acc[m2][n2][r] = z;
                }
                // carry == acc[3][n2][r] == C row (t_local=7), written below
            }
    }

#pragma unroll
    for (int m2 = 0; m2 < 4; ++m2) {
#pragma unroll
        for (int r = 0; r < 4; ++r) {
            size_t row = (size_t)(rowBase + wr * 64 + m2 * 16 + (lane >> 4) * 4 + r);
            float* po = Cout + row * P_DIM + colBase + wc * 32 + (lane & 15);
#pragma unroll
            for (int n2 = 0; n2 < 2; ++n2)
                po[n2 * 16] = acc[m2][n2][r] * INV_SCALE_B;
        }
    }
}

// ---------------------------------------------------------------------------
// Kernel C1 (fast): level-1 group scan. Carry of chunk c is read directly
// from the locally-scanned output: out[(c*8+7)*BP + bp].
// ---------------------------------------------------------------------------
__global__ __launch_bounds__(256) void group_scan_kernel(
    const float4* __restrict__ outbuf,
    const float4* __restrict__ aL8_4,
    float4* __restrict__ y,
    float4* __restrict__ G) {
    int tid = blockIdx.x * blockDim.x + threadIdx.x;  // NGROUPS*BP4
    int bp4 = tid & (BP4 - 1);
    int g = tid >> 11;
    float4 ab = aL8_4[bp4 & (P4 - 1)];
    float4 z = make_float4(0.f, 0.f, 0.f, 0.f);
#pragma unroll
    for (int j = 0; j < GROUP; ++j) {
        int c = g * GROUP + j;
        y[(size_t)c * BP4 + bp4] = z;
        float4 v = outbuf[(size_t)(c * CLEN_F + 7) * BP4 + bp4];
        z.x = fmaf(ab.x, z.x, v.x);
        z.y = fmaf(ab.y, z.y, v.y);
        z.z = fmaf(ab.z, z.z, v.z);
        z.w = fmaf(ab.w, z.w, v.w);
    }
    G[(size_t)g * BP4 + bp4] = z;
}

// ---------------------------------------------------------------------------
// Kernel C2 (fast): level-2 scan over the 32 group totals.
// ---------------------------------------------------------------------------
__global__ __launch_bounds__(256) void gcarry_scan_kernel(
    const float* __restrict__ G,
    const float* __restrict__ aL128,
    float* __restrict__ gz) {
    int bp = blockIdx.x * blockDim.x + threadIdx.x;  // 0..BP-1
    float aL = aL128[bp & (P_DIM - 1)];
    float z = 0.f;
#pragma unroll
    for (int g = 0; g < NGROUPS; ++g) {
        gz[g * BP + bp] = z;
        z = fmaf(aL, z, G[g * BP + bp]);
    }
}

// ---------------------------------------------------------------------------
// Kernel E (fast): fixup for chunks 1..511.
// ---------------------------------------------------------------------------
__global__ __launch_bounds__(256) void fixup8_kernel(
    float4* __restrict__ zio,
    const float4* __restrict__ a_bar4,
    const float4* __restrict__ y,
    const float4* __restrict__ gz,
    const float4* __restrict__ aL8pow4) {
    int tid = blockIdx.x * blockDim.x + threadIdx.x;  // (CHUNKS_F-1)*BP4
    int bp4 = tid & (BP4 - 1);
    int c = (tid >> 11) + 1;
    int p4 = bp4 & (P4 - 1);
    int g = c >> 4;
    int j = c & (GROUP - 1);
    float4 ab = a_bar4[p4];
    float4 pw = aL8pow4[j * P4 + p4];
    float4 yy = y[(size_t)c * BP4 + bp4];
    float4 gzz = gz[(size_t)g * BP4 + bp4];
    float4 zin;
    zin.x = fmaf(pw.x, gzz.x, yy.x);
    zin.y = fmaf(pw.y, gzz.y, yy.y);
    zin.z = fmaf(pw.z, gzz.z, yy.z);
    zin.w = fmaf(pw.w, gzz.w, yy.w);
    float4 f = ab;
    size_t base = (size_t)c * CLEN_F * BP4 + bp4;
#pragma unroll
    for (int i = 0; i < CLEN_F; ++i) {
        size_t off = base + (size_t)i * BP4;
        float4 v = zio[off];
        v.x = fmaf(f.x, zin.x, v.x);
        v.y = fmaf(f.y, zin.y, v.y);
        v.z = fmaf(f.z, zin.z, v.z);
        v.w = fmaf(f.w, zin.w, v.w);
        zio[off] = v;
        f.x *= ab.x;
        f.y *= ab.y;
        f.z *= ab.z;
        f.w *= ab.w;
    }
}

// ---------------------------------------------------------------------------
// Fallback fp32 path kernels (proven R1 structure).
// ---------------------------------------------------------------------------
#define BM 128
#define BN 128
#define BKF 16
__global__ __launch_bounds__(256) void gemm_kernel(
    const float* __restrict__ A,
    const float* __restrict__ Bm,
    float* __restrict__ Cout) {
    __shared__ float As[BM][BKF + 1];
    __shared__ float Bs[BN][BKF + 4];
    const int K = H_DIM;
    const int N = P_DIM;
    int tid = threadIdx.x;
    int tx = tid & 15;
    int ty = tid >> 4;
    int rowBase = blockIdx.y * BM;
    int colBase = blockIdx.x * BN;
    float acc[8][8];
#pragma unroll
    for (int i = 0; i < 8; ++i)
#pragma unroll
        for (int j = 0; j < 8; ++j) acc[i][j] = 0.f;
    for (int kt = 0; kt < K; kt += BKF) {
#pragma unroll
        for (int l = 0; l < 2; ++l) {
            int fl = tid * 2 + l;
            int row = fl >> 2;
            int kq = fl & 3;
            float4 av = *reinterpret_cast<const float4*>(
                &A[(size_t)(rowBase + row) * K + kt + kq * 4]);
            As[row][kq * 4 + 0] = av.x;
            As[row][kq * 4 + 1] = av.y;
            As[row][kq * 4 + 2] = av.z;
            As[row][kq * 4 + 3] = av.w;
            float4 bv = *reinterpret_cast<const float4*>(
                &Bm[(size_t)(colBase + row) * K + kt + kq * 4]);
            *reinterpret_cast<float4*>(&Bs[row][kq * 4]) = bv;
        }
        __syncthreads();
#pragma unroll
        for (int k = 0; k < BKF; ++k) {
            float af[8], bf[8];
#pragma unroll
            for (int i = 0; i < 8; ++i) af[i] = As[ty * 8 + i][k];
#pragma unroll
            for (int j = 0; j < 8; ++j) bf[j] = Bs[tx + 16 * j][k];
#pragma unroll
            for (int i = 0; i < 8; ++i)
#pragma unroll
                for (int j = 0; j < 8; ++j)
                    acc[i][j] = fmaf(af[i], bf[j], acc[i][j]);
        }
        __syncthreads();
    }
#pragma unroll
    for (int i = 0; i < 8; ++i) {
        size_t r = (size_t)(rowBase + ty * 8 + i);
#pragma unroll
        for (int j = 0; j < 8; ++j)
            Cout[r * N + colBase + tx + 16 * j] = acc[i][j];
    }
}

__global__ __launch_bounds__(256) void scan_local_kernel(
    float4* __restrict__ zio,
    const float4* __restrict__ a_bar4,
    float4* __restrict__ carry) {
    int tid = blockIdx.x * blockDim.x + threadIdx.x;
    int bp4 = tid & (BP4 - 1);
    int c = tid >> 11;
    float4 ab = a_bar4[bp4 & (P4 - 1)];
    size_t base = (size_t)c * CLEN_S * BP4 + bp4;
    float4 z = make_float4(0.f, 0.f, 0.f, 0.f);
    for (int i = 0; i < CLEN_S; ++i) {
        size_t off = base + (size_t)i * BP4;
        float4 v = zio[off];
        z.x = fmaf(ab.x, z.x, v.x);
        z.y = fmaf(ab.y, z.y, v.y);
        z.z = fmaf(ab.z, z.z, v.z);
        z.w = fmaf(ab.w, z.w, v.w);
        zio[off] = z;
    }
    carry[tid] = z;
}

__global__ __launch_bounds__(256) void carry_scan_kernel(
    const float4* __restrict__ carry,
    const float4* __restrict__ aL4,
    float4* __restrict__ z_in,
    int nchunks) {
    int bp4 = blockIdx.x * blockDim.x + threadIdx.x;
    float4 aL = aL4[bp4 & (P4 - 1)];
    float4 z = make_float4(0.f, 0.f, 0.f, 0.f);
    for (int c = 0; c < nchunks; ++c) {
        z_in[(size_t)c * BP4 + bp4] = z;
        float4 v = carry[(size_t)c * BP4 + bp4];
        z.x = fmaf(aL.x, z.x, v.x);
        z.y = fmaf(aL.y, z.y, v.y);
        z.z = fmaf(aL.z, z.z, v.z);
        z.w = fmaf(aL.w, z.w, v.w);
    }
}

__global__ __launch_bounds__(256) void fixup_kernel(
    float4* __restrict__ zio,
    const float4* __restrict__ a_bar4,
    const float4* __restrict__ z_in,
    int clen) {
    int tid = blockIdx.x * blockDim.x + threadIdx.x;
    int bp4 = tid & (BP4 - 1);
    int c = (tid >> 11) + 1;
    float4 ab = a_bar4[bp4 & (P4 - 1)];
    float4 zin = z_in[(size_t)c * BP4 + bp4];
    float4 f = ab;
    size_t base = (size_t)c * clen * BP4 + bp4;
    for (int i = 0; i < clen; ++i) {
        size_t off = base + (size_t)i * BP4;
        float4 v = zio[off];
        v.x = fmaf(f.x, zin.x, v.x);
        v.y = fmaf(f.y, zin.y, v.y);
        v.z = fmaf(f.z, zin.z, v.z);
        v.w = fmaf(f.w, zin.w, v.w);
        zio[off] = v;
        f.x *= ab.x;
        f.y *= ab.y;
        f.z *= ab.z;
        f.w *= ab.w;
    }
}

// ---------------------------------------------------------------------------
extern "C" void kernel_launch(void* const* d_in, const int* in_sizes, int n_in,
                              void* d_out, int out_size, void* d_ws, size_t ws_size,
                              hipStream_t stream) {
    const float* inputs    = (const float*)d_in[0];  // [T, B, H]
    const float* log_neg_a = (const float*)d_in[1];  // [P]
    const float* b         = (const float*)d_in[2];  // [P, H]
    const float* log_dt    = (const float*)d_in[3];  // [P]
    float* out = (float*)d_out;                      // [T, B, P]
    float* ws  = (float*)d_ws;

    // workspace layout (float units)
    float* b_bar   = ws;                              // 262144
    float* a_bar   = b_bar + P_DIM * H_DIM;           // 512
    float* aL8     = a_bar + P_DIM;                   // 512
    float* aL128   = aL8 + P_DIM;                     // 512
    float* aL64    = aL128 + P_DIM;                   // 512
    float* aL8pow  = aL64 + P_DIM;                    // GROUP*P = 8192
    float* carry   = aL8pow + GROUP * P_DIM;          // CHUNKS_F*BP (fallback only)
    float* y       = carry + (size_t)CHUNKS_F * BP;   // 4194304 (also fallback z_in)
    float* G       = y + (size_t)CHUNKS_F * BP;       // NGROUPS*BP = 262144
    float* gz      = G + (size_t)NGROUPS * BP;        // 262144
    float* tail    = gz + (size_t)NGROUPS * BP;
    _Float16* b_bar16 = (_Float16*)tail;              // 262144 halfs

    size_t ws_need = (size_t)((char*)(b_bar16 + (size_t)P_DIM * H_DIM) - (char*)ws);
    int fast = (ws_size >= ws_need);

    precompute_kernel<<<(P_DIM * H_DIM) / 256, 256, 0, stream>>>(
        log_neg_a, b, log_dt, b_bar, b_bar16, a_bar, aL8, aL128, aL64, aL8pow, fast);

    if (fast) {
        // 1-D grid of 4096 (128x64 tiles), XCD-swizzled inside the kernel.
        // A is consumed directly as f32 (reg-staged cvt) — no convert pass.
        gemm_regA_scan_kernel<<<4096, 256, 0, stream>>>(
            inputs, (const char*)b_bar16, a_bar, out);

        group_scan_kernel<<<(NGROUPS * BP4) / 256, 256, 0, stream>>>(
            (const float4*)out, (const float4*)aL8, (float4*)y, (float4*)G);

        gcarry_scan_kernel<<<BP / 256, 256, 0, stream>>>(G, aL128, gz);

        fixup8_kernel<<<((CHUNKS_F - 1) * BP4) / 256, 256, 0, stream>>>(
            (float4*)out, (const float4*)a_bar, (const float4*)y,
            (const float4*)gz, (const float4*)aL8pow);
    } else {
        dim3 ggrid(P_DIM / BN, M_DIM / BM);
        gemm_kernel<<<ggrid, 256, 0, stream>>>(inputs, b_bar, out);

        scan_local_kernel<<<(CHUNKS_S * BP4) / 256, 256, 0, stream>>>(
            (float4*)out, (const float4*)a_bar, (float4*)carry);

        carry_scan_kernel<<<BP4 / 256, 256, 0, stream>>>(
            (const float4*)carry, (const float4*)aL64, (float4*)y, CHUNKS_S);

        fixup_kernel<<<((CHUNKS_S - 1) * BP4) / 256, 256, 0, stream>>>(
            (float4*)out, (const float4*)a_bar, (const float4*)y, CLEN_S);
    }
}

// Round 14
// 144.593 us; speedup vs baseline: 1.2086x; 1.2086x over previous
//
#include <hip/hip_runtime.h>
#include <math.h>

#define T_DIM 4096
#define B_DIM 16
#define P_DIM 512
#define H_DIM 512
#define M_DIM (T_DIM * B_DIM)   // 65536
#define BP (B_DIM * P_DIM)      // 8192
#define BP4 (BP / 4)            // 2048
#define P4 (P_DIM / 4)          // 128

#define KBYTES (H_DIM * 2)      // f16 row bytes = 1024
#define BK 64
#define NKT (H_DIM / BK)        // 8 k-tiles

// fused path: chunk = 8 timesteps (one 128-row GEMM tile)
#define CLEN_F 8
#define CHUNKS_F (T_DIM / CLEN_F)   // 512
#define GROUP 16                    // chunks per group in carry hierarchy
#define NGROUPS (CHUNKS_F / GROUP)  // 32
// fallback (fp32) path: chunk = 64 timesteps
#define CLEN_S 64
#define CHUNKS_S (T_DIM / CLEN_S)   // 64

#define SCALE_B 1048576.0f          // 2^20: lifts b_bar out of f16 subnormal range
#define INV_SCALE_B (1.0f / 1048576.0f)

typedef _Float16 f16x8 __attribute__((ext_vector_type(8)));
typedef float f32x4 __attribute__((ext_vector_type(4)));

__device__ __forceinline__ void gload16(const void* g, void* l) {
    __builtin_amdgcn_global_load_lds(
        (const __attribute__((address_space(1))) void*)(uintptr_t)g,
        (__attribute__((address_space(3))) void*)(uint32_t)(uintptr_t)l,
        16, 0, 0);
}

// ---------------------------------------------------------------------------
// Kernel A: discretization + per-p scan coefficients.
// ---------------------------------------------------------------------------
__global__ __launch_bounds__(256) void precompute_kernel(
    const float* __restrict__ log_neg_a,
    const float* __restrict__ b,
    const float* __restrict__ log_dt,
    float* __restrict__ b_bar,
    _Float16* __restrict__ b_bar16,
    float* __restrict__ a_bar,
    float* __restrict__ aL8,
    float* __restrict__ aL128,
    float* __restrict__ aL64,
    float* __restrict__ aL8pow,
    int write16) {
    int idx = blockIdx.x * blockDim.x + threadIdx.x;
    if (idx >= P_DIM * H_DIM) return;
    int p = idx >> 9;
    float dt = expf(log_dt[p]);
    float a  = -expf(log_neg_a[p]);
    float x  = dt * a;
    float scale = (expm1f(x) / a) * dt;
    float bb = scale * b[idx];
    b_bar[idx] = bb;
    if (write16) b_bar16[idx] = (_Float16)(bb * SCALE_B);
    if ((idx & (H_DIM - 1)) == 0) {
        a_bar[p] = expf(x);
        float l8 = expf(x * 8.0f);
        aL8[p]   = l8;
        aL128[p] = expf(x * 128.0f);
        aL64[p]  = expf(x * 64.0f);
        float pw = 1.0f;
        for (int j = 0; j < GROUP; ++j) {
            aL8pow[j * P_DIM + p] = pw;
            pw *= l8;
        }
    }
}

// ---------------------------------------------------------------------------
// Kernel A2: fp32 -> f16 conversion of inputs (8 floats / thread).
// HBM floor (~33 µs for 192 MB). Reg-staged alternatives measured worse
// twice (R6: 110 µs kernel, R13: 135 µs kernel vs 78+33 here).
// ---------------------------------------------------------------------------
__global__ __launch_bounds__(256) void convert_a_kernel(
    const float4* __restrict__ in, f16x8* __restrict__ out) {
    int t = blockIdx.x * blockDim.x + threadIdx.x;
    float4 v0 = in[(size_t)t * 2];
    float4 v1 = in[(size_t)t * 2 + 1];
    f16x8 o;
    o[0] = (_Float16)v0.x; o[1] = (_Float16)v0.y;
    o[2] = (_Float16)v0.z; o[3] = (_Float16)v0.w;
    o[4] = (_Float16)v1.x; o[5] = (_Float16)v1.y;
    o[6] = (_Float16)v1.z; o[7] = (_Float16)v1.w;
    out[t] = o;
}

// ---------------------------------------------------------------------------
// Kernel B (fast): f16 MFMA NT GEMM, 128x64 tile (best measured: R12).
// 24 KB LDS + VGPR 40 -> 6 blocks/CU, 37% occupancy. global_load_lds
// staging, both-sides XOR swizzle, XCD-aware block swizzle, fused 8-step
// chunk-local time scan. Carry == last-timestep output row (not stored).
// ---------------------------------------------------------------------------
__global__ __launch_bounds__(256, 6) void gemm16_scan_kernel(
    const char* __restrict__ A16,
    const char* __restrict__ B16,
    const float* __restrict__ a_bar,
    float* __restrict__ Cout) {
    __shared__ char As[128 * BK * 2];   // 16 KB
    __shared__ char Bs[64 * BK * 2];    // 8 KB

    const int tid  = threadIdx.x;
    const int lane = tid & 63;
    const int wid  = tid >> 6;

    // T1 swizzle: 4096 blocks, l%8 -> XCD; the 8 col-blocks of a row-panel
    // run consecutively on one XCD.
    const int l   = blockIdx.x;           // 0..4095
    const int k8  = l & 7;
    const int j   = l >> 3;               // 0..511
    const int by  = k8 * 64 + (j >> 3);   // row-block (= chunk id), 0..511
    const int bx  = j & 7;                // col-block, 0..7
    const int rowBase = by * 128;
    const int colBase = bx * 64;

    const int srow = tid >> 3;            // 0..31
    const int scol = ((tid & 7) << 4) ^ ((srow & 7) << 4);
    const char* gA = A16 + (size_t)(rowBase + srow) * KBYTES + scol;
    const char* gB = B16 + (size_t)(colBase + srow) * KBYTES + scol;

    f32x4 acc[4][2];
#pragma unroll
    for (int m2 = 0; m2 < 4; ++m2)
#pragma unroll
        for (int n2 = 0; n2 < 2; ++n2)
            acc[m2][n2] = (f32x4){0.f, 0.f, 0.f, 0.f};

    const int wr = wid >> 1;   // row half (64 rows = 4 timesteps)
    const int wc = wid & 1;    // col half (32 cols)

    for (int kt = 0; kt < NKT; ++kt) {
        // A: 128 rows = 1024 chunks = 4 issues of 256
#pragma unroll
        for (int i = 0; i < 4; ++i)
            gload16(gA + (size_t)i * 32 * KBYTES, As + (i * 256 + tid) * 16);
        // B: 64 rows = 512 chunks = 2 issues of 256
#pragma unroll
        for (int i = 0; i < 2; ++i)
            gload16(gB + (size_t)i * 32 * KBYTES, Bs + (i * 256 + tid) * 16);
        gA += BK * 2;
        gB += BK * 2;
        __syncthreads();

#pragma unroll
        for (int kk = 0; kk < 2; ++kk) {
            const int kbyte = kk * 64 + ((lane >> 4) << 4);
            f16x8 af[4], bf[2];
#pragma unroll
            for (int m2 = 0; m2 < 4; ++m2) {
                int row = wr * 64 + m2 * 16 + (lane & 15);
                af[m2] = *(const f16x8*)(As + row * 128 + (kbyte ^ ((row & 7) << 4)));
            }
#pragma unroll
            for (int n2 = 0; n2 < 2; ++n2) {
                int col = wc * 32 + n2 * 16 + (lane & 15);
                bf[n2] = *(const f16x8*)(Bs + col * 128 + (kbyte ^ ((col & 7) << 4)));
            }
#pragma unroll
            for (int m2 = 0; m2 < 4; ++m2)
#pragma unroll
                for (int n2 = 0; n2 < 2; ++n2)
                    acc[m2][n2] = __builtin_amdgcn_mfma_f32_16x16x32_f16(
                        af[m2], bf[n2], acc[m2][n2], 0, 0, 0);
        }
        __syncthreads();
    }

    // ---- fused chunk-local scan over the block's 8 timesteps ----
    float* lds_z = (float*)As;               // [16 b][64 p_local]
    const int pl = wc * 32 + (lane & 15);

    float ab[2];
#pragma unroll
    for (int n2 = 0; n2 < 2; ++n2) ab[n2] = a_bar[colBase + pl + n2 * 16];

    if (wr == 0) {
#pragma unroll
        for (int n2 = 0; n2 < 2; ++n2)
#pragma unroll
            for (int r = 0; r < 4; ++r) {
                float z = 0.f;
#pragma unroll
                for (int m2 = 0; m2 < 4; ++m2) {
                    z = fmaf(ab[n2], z, acc[m2][n2][r]);
                    acc[m2][n2][r] = z;
                }
                lds_z[((lane >> 4) * 4 + r) * 64 + pl + n2 * 16] = z;
            }
    }
    __syncthreads();
    if (wr == 1) {
#pragma unroll
        for (int n2 = 0; n2 < 2; ++n2)
#pragma unroll
            for (int r = 0; r < 4; ++r) {
                float z = lds_z[((lane >> 4) * 4 + r) * 64 + pl + n2 * 16];
#pragma unroll
                for (int m2 = 0; m2 < 4; ++m2) {
                    z = fmaf(ab[n2], z, acc[m2][n2][r]);
                    acc[m2][n2][r] = z;
                }
                // carry == acc[3][n2][r] == C row (t_local=7) — written below.
            }
    }

#pragma unroll
    for (int m2 = 0; m2 < 4; ++m2) {
#pragma unroll
        for (int r = 0; r < 4; ++r) {
            size_t row = (size_t)(rowBase + wr * 64 + m2 * 16 + (lane >> 4) * 4 + r);
            float* po = Cout + row * P_DIM + colBase + wc * 32 + (lane & 15);
#pragma unroll
            for (int n2 = 0; n2 < 2; ++n2)
                po[n2 * 16] = acc[m2][n2][r] * INV_SCALE_B;
        }
    }
}

// ---------------------------------------------------------------------------
// Kernel C1 (fast): level-1 group scan. Carry of chunk c is read directly
// from the locally-scanned output: out[(c*8+7)*BP + bp].
// ---------------------------------------------------------------------------
__global__ __launch_bounds__(256) void group_scan_kernel(
    const float4* __restrict__ outbuf,
    const float4* __restrict__ aL8_4,
    float4* __restrict__ y,
    float4* __restrict__ G) {
    int tid = blockIdx.x * blockDim.x + threadIdx.x;  // NGROUPS*BP4
    int bp4 = tid & (BP4 - 1);
    int g = tid >> 11;
    float4 ab = aL8_4[bp4 & (P4 - 1)];
    float4 z = make_float4(0.f, 0.f, 0.f, 0.f);
#pragma unroll
    for (int j = 0; j < GROUP; ++j) {
        int c = g * GROUP + j;
        y[(size_t)c * BP4 + bp4] = z;
        float4 v = outbuf[(size_t)(c * CLEN_F + 7) * BP4 + bp4];
        z.x = fmaf(ab.x, z.x, v.x);
        z.y = fmaf(ab.y, z.y, v.y);
        z.z = fmaf(ab.z, z.z, v.z);
        z.w = fmaf(ab.w, z.w, v.w);
    }
    G[(size_t)g * BP4 + bp4] = z;
}

// ---------------------------------------------------------------------------
// Kernel C2 (fast): level-2 scan over the 32 group totals.
// ---------------------------------------------------------------------------
__global__ __launch_bounds__(256) void gcarry_scan_kernel(
    const float* __restrict__ G,
    const float* __restrict__ aL128,
    float* __restrict__ gz) {
    int bp = blockIdx.x * blockDim.x + threadIdx.x;  // 0..BP-1
    float aL = aL128[bp & (P_DIM - 1)];
    float z = 0.f;
#pragma unroll
    for (int g = 0; g < NGROUPS; ++g) {
        gz[g * BP + bp] = z;
        z = fmaf(aL, z, G[g * BP + bp]);
    }
}

// ---------------------------------------------------------------------------
// Kernel E (fast): fixup for chunks 1..511.
// ---------------------------------------------------------------------------
__global__ __launch_bounds__(256) void fixup8_kernel(
    float4* __restrict__ zio,
    const float4* __restrict__ a_bar4,
    const float4* __restrict__ y,
    const float4* __restrict__ gz,
    const float4* __restrict__ aL8pow4) {
    int tid = blockIdx.x * blockDim.x + threadIdx.x;  // (CHUNKS_F-1)*BP4
    int bp4 = tid & (BP4 - 1);
    int c = (tid >> 11) + 1;
    int p4 = bp4 & (P4 - 1);
    int g = c >> 4;
    int j = c & (GROUP - 1);
    float4 ab = a_bar4[p4];
    float4 pw = aL8pow4[j * P4 + p4];
    float4 yy = y[(size_t)c * BP4 + bp4];
    float4 gzz = gz[(size_t)g * BP4 + bp4];
    float4 zin;
    zin.x = fmaf(pw.x, gzz.x, yy.x);
    zin.y = fmaf(pw.y, gzz.y, yy.y);
    zin.z = fmaf(pw.z, gzz.z, yy.z);
    zin.w = fmaf(pw.w, gzz.w, yy.w);
    float4 f = ab;
    size_t base = (size_t)c * CLEN_F * BP4 + bp4;
#pragma unroll
    for (int i = 0; i < CLEN_F; ++i) {
        size_t off = base + (size_t)i * BP4;
        float4 v = zio[off];
        v.x = fmaf(f.x, zin.x, v.x);
        v.y = fmaf(f.y, zin.y, v.y);
        v.z = fmaf(f.z, zin.z, v.z);
        v.w = fmaf(f.w, zin.w, v.w);
        zio[off] = v;
        f.x *= ab.x;
        f.y *= ab.y;
        f.z *= ab.z;
        f.w *= ab.w;
    }
}

// ---------------------------------------------------------------------------
// Fallback fp32 path kernels (proven R1 structure).
// ---------------------------------------------------------------------------
#define BM 128
#define BN 128
#define BKF 16
__global__ __launch_bounds__(256) void gemm_kernel(
    const float* __restrict__ A,
    const float* __restrict__ Bm,
    float* __restrict__ Cout) {
    __shared__ float As[BM][BKF + 1];
    __shared__ float Bs[BN][BKF + 4];
    const int K = H_DIM;
    const int N = P_DIM;
    int tid = threadIdx.x;
    int tx = tid & 15;
    int ty = tid >> 4;
    int rowBase = blockIdx.y * BM;
    int colBase = blockIdx.x * BN;
    float acc[8][8];
#pragma unroll
    for (int i = 0; i < 8; ++i)
#pragma unroll
        for (int j = 0; j < 8; ++j) acc[i][j] = 0.f;
    for (int kt = 0; kt < K; kt += BKF) {
#pragma unroll
        for (int l = 0; l < 2; ++l) {
            int fl = tid * 2 + l;
            int row = fl >> 2;
            int kq = fl & 3;
            float4 av = *reinterpret_cast<const float4*>(
                &A[(size_t)(rowBase + row) * K + kt + kq * 4]);
            As[row][kq * 4 + 0] = av.x;
            As[row][kq * 4 + 1] = av.y;
            As[row][kq * 4 + 2] = av.z;
            As[row][kq * 4 + 3] = av.w;
            float4 bv = *reinterpret_cast<const float4*>(
                &Bm[(size_t)(colBase + row) * K + kt + kq * 4]);
            *reinterpret_cast<float4*>(&Bs[row][kq * 4]) = bv;
        }
        __syncthreads();
#pragma unroll
        for (int k = 0; k < BKF; ++k) {
            float af[8], bf[8];
#pragma unroll
            for (int i = 0; i < 8; ++i) af[i] = As[ty * 8 + i][k];
#pragma unroll
            for (int j = 0; j < 8; ++j) bf[j] = Bs[tx + 16 * j][k];
#pragma unroll
            for (int i = 0; i < 8; ++i)
#pragma unroll
                for (int j = 0; j < 8; ++j)
                    acc[i][j] = fmaf(af[i], bf[j], acc[i][j]);
        }
        __syncthreads();
    }
#pragma unroll
    for (int i = 0; i < 8; ++i) {
        size_t r = (size_t)(rowBase + ty * 8 + i);
#pragma unroll
        for (int j = 0; j < 8; ++j)
            Cout[r * N + colBase + tx + 16 * j] = acc[i][j];
    }
}

__global__ __launch_bounds__(256) void scan_local_kernel(
    float4* __restrict__ zio,
    const float4* __restrict__ a_bar4,
    float4* __restrict__ carry) {
    int tid = blockIdx.x * blockDim.x + threadIdx.x;
    int bp4 = tid & (BP4 - 1);
    int c = tid >> 11;
    float4 ab = a_bar4[bp4 & (P4 - 1)];
    size_t base = (size_t)c * CLEN_S * BP4 + bp4;
    float4 z = make_float4(0.f, 0.f, 0.f, 0.f);
    for (int i = 0; i < CLEN_S; ++i) {
        size_t off = base + (size_t)i * BP4;
        float4 v = zio[off];
        z.x = fmaf(ab.x, z.x, v.x);
        z.y = fmaf(ab.y, z.y, v.y);
        z.z = fmaf(ab.z, z.z, v.z);
        z.w = fmaf(ab.w, z.w, v.w);
        zio[off] = z;
    }
    carry[tid] = z;
}

__global__ __launch_bounds__(256) void carry_scan_kernel(
    const float4* __restrict__ carry,
    const float4* __restrict__ aL4,
    float4* __restrict__ z_in,
    int nchunks) {
    int bp4 = blockIdx.x * blockDim.x + threadIdx.x;
    float4 aL = aL4[bp4 & (P4 - 1)];
    float4 z = make_float4(0.f, 0.f, 0.f, 0.f);
    for (int c = 0; c < nchunks; ++c) {
        z_in[(size_t)c * BP4 + bp4] = z;
        float4 v = carry[(size_t)c * BP4 + bp4];
        z.x = fmaf(aL.x, z.x, v.x);
        z.y = fmaf(aL.y, z.y, v.y);
        z.z = fmaf(aL.z, z.z, v.z);
        z.w = fmaf(aL.w, z.w, v.w);
    }
}

__global__ __launch_bounds__(256) void fixup_kernel(
    float4* __restrict__ zio,
    const float4* __restrict__ a_bar4,
    const float4* __restrict__ z_in,
    int clen) {
    int tid = blockIdx.x * blockDim.x + threadIdx.x;
    int bp4 = tid & (BP4 - 1);
    int c = (tid >> 11) + 1;
    float4 ab = a_bar4[bp4 & (P4 - 1)];
    float4 zin = z_in[(size_t)c * BP4 + bp4];
    float4 f = ab;
    size_t base = (size_t)c * clen * BP4 + bp4;
    for (int i = 0; i < clen; ++i) {
        size_t off = base + (size_t)i * BP4;
        float4 v = zio[off];
        v.x = fmaf(f.x, zin.x, v.x);
        v.y = fmaf(f.y, zin.y, v.y);
        v.z = fmaf(f.z, zin.z, v.z);
        v.w = fmaf(f.w, zin.w, v.w);
        zio[off] = v;
        f.x *= ab.x;
        f.y *= ab.y;
        f.z *= ab.z;
        f.w *= ab.w;
    }
}

// ---------------------------------------------------------------------------
extern "C" void kernel_launch(void* const* d_in, const int* in_sizes, int n_in,
                              void* d_out, int out_size, void* d_ws, size_t ws_size,
                              hipStream_t stream) {
    const float* inputs    = (const float*)d_in[0];  // [T, B, H]
    const float* log_neg_a = (const float*)d_in[1];  // [P]
    const float* b         = (const float*)d_in[2];  // [P, H]
    const float* log_dt    = (const float*)d_in[3];  // [P]
    float* out = (float*)d_out;                      // [T, B, P]
    float* ws  = (float*)d_ws;

    // workspace layout (float units)
    float* b_bar   = ws;                              // 262144
    float* a_bar   = b_bar + P_DIM * H_DIM;           // 512
    float* aL8     = a_bar + P_DIM;                   // 512
    float* aL128   = aL8 + P_DIM;                     // 512
    float* aL64    = aL128 + P_DIM;                   // 512
    float* aL8pow  = aL64 + P_DIM;                    // GROUP*P = 8192
    float* carry   = aL8pow + GROUP * P_DIM;          // CHUNKS_F*BP (fallback only)
    float* y       = carry + (size_t)CHUNKS_F * BP;   // 4194304 (also fallback z_in)
    float* G       = y + (size_t)CHUNKS_F * BP;       // NGROUPS*BP = 262144
    float* gz      = G + (size_t)NGROUPS * BP;        // 262144
    float* tail    = gz + (size_t)NGROUPS * BP;
    _Float16* b_bar16 = (_Float16*)tail;              // 262144 halfs
    _Float16* A16     = b_bar16 + P_DIM * H_DIM;      // 33554432 halfs

    size_t ws_need = (size_t)((char*)(A16 + (size_t)M_DIM * H_DIM) - (char*)ws);
    int fast = (ws_size >= ws_need);

    precompute_kernel<<<(P_DIM * H_DIM) / 256, 256, 0, stream>>>(
        log_neg_a, b, log_dt, b_bar, b_bar16, a_bar, aL8, aL128, aL64, aL8pow, fast);

    if (fast) {
        convert_a_kernel<<<(M_DIM * H_DIM / 8) / 256, 256, 0, stream>>>(
            (const float4*)inputs, (f16x8*)A16);

        // 1-D grid of 4096 (128x64 tiles), XCD-swizzled inside the kernel
        gemm16_scan_kernel<<<4096, 256, 0, stream>>>(
            (const char*)A16, (const char*)b_bar16, a_bar, out);

        group_scan_kernel<<<(NGROUPS * BP4) / 256, 256, 0, stream>>>(
            (const float4*)out, (const float4*)aL8, (float4*)y, (float4*)G);

        gcarry_scan_kernel<<<BP / 256, 256, 0, stream>>>(G, aL128, gz);

        fixup8_kernel<<<((CHUNKS_F - 1) * BP4) / 256, 256, 0, stream>>>(
            (float4*)out, (const float4*)a_bar, (const float4*)y,
            (const float4*)gz, (const float4*)aL8pow);
    } else {
        dim3 ggrid(P_DIM / BN, M_DIM / BM);
        gemm_kernel<<<ggrid, 256, 0, stream>>>(inputs, b_bar, out);

        scan_local_kernel<<<(CHUNKS_S * BP4) / 256, 256, 0, stream>>>(
            (float4*)out, (const float4*)a_bar, (float4*)carry);

        carry_scan_kernel<<<BP4 / 256, 256, 0, stream>>>(
            (const float4*)carry, (const float4*)aL64, (float4*)y, CHUNKS_S);

        fixup_kernel<<<((CHUNKS_S - 1) * BP4) / 256, 256, 0, stream>>>(
            (float4*)out, (const float4*)a_bar, (const float4*)y, CLEN_S);
    }
}